// Round 25
// baseline (28.819 us; speedup 1.0000x reference)
//
#include <hip/hip_runtime.h>
#include <hip/hip_fp16.h>

typedef _Float16 f16x8 __attribute__((ext_vector_type(8)));
typedef _Float16 f16x2 __attribute__((ext_vector_type(2)));
typedef float f32x4 __attribute__((ext_vector_type(4)));

namespace {
constexpr int K = 4096;
constexpr int N = 11008;
constexpr int NC = N / 8;            // 1376 packed words per K-row
constexpr int KSPLIT = 16;           // 256-deep K slices (2 quant groups)
constexpr int SLICE_K = K / KSPLIT;  // 256
constexpr int BXW = 32;              // word-cols per block (256 output cols)
constexpr int BK = 32;               // K rows per MFMA step
constexpr int NT = SLICE_K / BK;     // 8 steps
constexpr int QS = SLICE_K + 4;      // q LDS col stride, words (260)
constexpr int XSH = 272;             // x LDS row stride, halfs
constexpr int OUT_ELEMS = 32 * N;    // 352256
constexpr int NBX = NC / BXW;        // 43 column tiles
constexpr int NWG = NBX * KSPLIT;    // 688 blocks
constexpr int PER_XCD = NWG / 8;     // 86
constexpr int TILE_W = SLICE_K * BXW;       // 8192 words = 32KB per tile
constexpr int LSTR = 1380;           // transform LDS row stride (words)
}

// Relay qweight through L2 in a GEMM-friendly tiled layout.
// Each block: 16 contiguous rows (88KB) read SEQUENTIALLY -> LDS ->
// 43 tiles x 2KB contiguous writes. Block->XCD remap makes each XCD
// produce exactly the tiles its GEMM blocks (r24 swizzle) will read.
__global__ __launch_bounds__(512) void transform_kernel(
    const int* __restrict__ qw, int* __restrict__ tiled) {
  __shared__ int lds[16 * LSTR];   // 88,320 B
  const int tid = threadIdx.x;
  const int j   = blockIdx.x;                 // 0..255, XCD = j%8 (round-robin)
  const int r16 = (j & 7) * 32 + (j >> 3);    // 16-row chunk, XCD-aligned
  const int k0  = r16 * 16;
  const int by  = r16 >> 4;                   // k-slice 0..15 (XCD = by>>1 = j&7)
  const int koff = k0 & (SLICE_K - 1);

  // sequential read: 5504 int4 = 16 rows x 1376 words
  const int4* src = reinterpret_cast<const int4*>(qw + (long)k0 * NC);
#pragma unroll
  for (int r = 0; r < 11; ++r) {
    const int idx = r * 512 + tid;
    if (idx < 5504) {
      const int4 v = src[idx];
      const int row = idx / 344;              // 344 int4 per source row
      const int col = (idx - row * 344) * 4;  // word within row
      *reinterpret_cast<int4*>(&lds[row * LSTR + col]) = v;
    }
  }
  __syncthreads();

  // tiled write: tile bxt gets rows k0..k0+15 x words bxt*32..+31 (2KB contig)
#pragma unroll
  for (int w = 0; w < 11; ++w) {
    const int idx = w * 512 + tid;
    if (idx < 5504) {
      const int bxt = idx >> 7;               // 0..42
      const int wi  = idx & 127;
      const int k   = wi >> 3;                // 0..15
      const int wg  = wi & 7;
      const int4 v = *reinterpret_cast<const int4*>(&lds[k * LSTR + bxt * 32 + wg * 4]);
      *reinterpret_cast<int4*>(
          &tiled[(long)(by * NBX + bxt) * TILE_W + (koff + k) * 32 + wg * 4]) = v;
    }
  }
}

// sum 16 f16 K-slice partials + bias -> out (8 outputs per thread)
__global__ void reduce_kernel(const _Float16* __restrict__ partial,
                              const float* __restrict__ bias,
                              float* __restrict__ out) {
  const int idx = (blockIdx.x * 256 + threadIdx.x) * 8;   // 172 blocks exact
  const int n = idx % N;
  const float4 b0 = *reinterpret_cast<const float4*>(bias + n);
  const float4 b1 = *reinterpret_cast<const float4*>(bias + n + 4);
  float a[8] = {b0.x, b0.y, b0.z, b0.w, b1.x, b1.y, b1.z, b1.w};
#pragma unroll
  for (int s = 0; s < KSPLIT; ++s) {
    const f16x8 p = *reinterpret_cast<const f16x8*>(partial + (long)s * OUT_ELEMS + idx);
#pragma unroll
    for (int j = 0; j < 8; ++j) a[j] += (float)p[j];
  }
  float4 o0 = {a[0], a[1], a[2], a[3]}, o1 = {a[4], a[5], a[6], a[7]};
  *reinterpret_cast<float4*>(out + idx)     = o0;
  *reinterpret_cast<float4*>(out + idx + 4) = o1;
}

// r24 body; q now read from the tiled layout: 4 x 8KB-contiguous rounds
// (L2-hit on the producing XCD, or sequential-HBM fallback — both fast).
__global__ __launch_bounds__(512, 4) void awq_gemm_kernel(
    const int* __restrict__ tiled, const int* __restrict__ qz,
    const float* __restrict__ sc, const float* __restrict__ x,
    _Float16* __restrict__ partial)
{
  __shared__ int lqs[BXW * QS];         // q tile, col-major [word-col][k]
  __shared__ _Float16 lxh[32 * XSH];    // x tile f16, [row][k]

  const int tid  = threadIdx.x;
  const int lane = tid & 63;
  const int wid  = tid >> 6;      // wave 0..7
  const int kq   = lane >> 4;     // 0..3
  const int c16  = lane & 15;

  // XCD swizzle (r24): XCD q owns by in {2q,2q+1} -> matches transform producer
  const int wg  = blockIdx.x;
  const int wgp = (wg & 7) * PER_XCD + (wg >> 3);
  const int by  = wgp / NBX;
  const int bx  = wgp % NBX;

  const int n0 = bx * (BXW * 8);
  const int c0 = bx * BXW;

  // AWQ nibble shift for col (n&7): 4*AWQ_ORDER[n&7], order [0,4,1,5,2,6,3,7]
  const int j7 = c16 & 7;
  const int sh = ((j7 >> 1) | ((j7 & 1) << 2)) << 2;

  int ncol[2], cglob[2], cloc[2];
#pragma unroll
  for (int t2 = 0; t2 < 2; ++t2) {
    ncol[t2]  = n0 + wid * 32 + t2 * 16 + c16;
    cglob[t2] = ncol[t2] >> 3;
    cloc[t2]  = wid * 4 + t2 * 2 + (c16 >> 3);
  }

  const int kbeg = by * SLICE_K;
  const int g0   = kbeg >> 7;

  // ---- q: 4 rounds of 8KB-contiguous block reads from the tile ----
  const int4* tsrc = reinterpret_cast<const int4*>(tiled) + (long)(by * NBX + bx) * (TILE_W / 4);
  int4 qv[4];
#pragma unroll
  for (int rr = 0; rr < 4; ++rr)
    qv[rr] = tsrc[rr * 512 + tid];            // int4 idx = k*8+wg

  const int xm = tid >> 4;
  const int xo = tid & 15;
  const float* xrow = x + (long)xm * K + kbeg + xo * 16;
  const float4 xa = *reinterpret_cast<const float4*>(xrow);
  const float4 xb = *reinterpret_cast<const float4*>(xrow + 4);
  const float4 xc = *reinterpret_cast<const float4*>(xrow + 8);
  const float4 xd = *reinterpret_cast<const float4*>(xrow + 12);

  f16x2 s2[2][2], mz2[2][2];
#pragma unroll
  for (int g = 0; g < 2; ++g)
#pragma unroll
    for (int t2 = 0; t2 < 2; ++t2) {
      const int zq = qz[(g0 + g) * NC + cglob[t2]];
      const _Float16 s16 = (_Float16)sc[(g0 + g) * N + ncol[t2]];
      const _Float16 mz  = (_Float16)(-(float)(1024 + ((zq >> sh) & 15)));
      s2[g][t2][0] = s16; s2[g][t2][1] = s16;
      mz2[g][t2][0] = mz; mz2[g][t2][1] = mz;
    }

  // ---- LDS writes (int4 idx -> k = idx>>3, wg = idx&7; same as r21 geometry)
  const int qr = tid >> 3;        // k within 64-row round
  const int qc = tid & 7;         // word group
#pragma unroll
  for (int rr = 0; rr < 4; ++rr) {
    const int r = rr * 64 + qr;
    lqs[(qc * 4 + 0) * QS + r] = qv[rr].x;
    lqs[(qc * 4 + 1) * QS + r] = qv[rr].y;
    lqs[(qc * 4 + 2) * QS + r] = qv[rr].z;
    lqs[(qc * 4 + 3) * QS + r] = qv[rr].w;
  }
  {
    union { f16x2 h2[4]; f16x8 h8; } u0, u1;
    u0.h2[0] = __builtin_bit_cast(f16x2, __builtin_amdgcn_cvt_pkrtz(xa.x, xa.y));
    u0.h2[1] = __builtin_bit_cast(f16x2, __builtin_amdgcn_cvt_pkrtz(xa.z, xa.w));
    u0.h2[2] = __builtin_bit_cast(f16x2, __builtin_amdgcn_cvt_pkrtz(xb.x, xb.y));
    u0.h2[3] = __builtin_bit_cast(f16x2, __builtin_amdgcn_cvt_pkrtz(xb.z, xb.w));
    u1.h2[0] = __builtin_bit_cast(f16x2, __builtin_amdgcn_cvt_pkrtz(xc.x, xc.y));
    u1.h2[1] = __builtin_bit_cast(f16x2, __builtin_amdgcn_cvt_pkrtz(xc.z, xc.w));
    u1.h2[2] = __builtin_bit_cast(f16x2, __builtin_amdgcn_cvt_pkrtz(xd.x, xd.y));
    u1.h2[3] = __builtin_bit_cast(f16x2, __builtin_amdgcn_cvt_pkrtz(xd.z, xd.w));
    _Float16* dst = &lxh[xm * XSH + xo * 16];
    *reinterpret_cast<f16x8*>(dst)     = u0.h8;
    *reinterpret_cast<f16x8*>(dst + 8) = u1.h8;
  }

  __syncthreads();               // the ONLY barrier

  f32x4 acc[2][2] = {};

#pragma unroll
  for (int t = 0; t < NT; ++t) {
    const int g = t >> 2;
    const f16x8 a0 = *reinterpret_cast<const f16x8*>(&lxh[c16 * XSH + t * BK + kq * 8]);
    const f16x8 a1 = *reinterpret_cast<const f16x8*>(&lxh[(c16 + 16) * XSH + t * BK + kq * 8]);

#pragma unroll
    for (int t2 = 0; t2 < 2; ++t2) {
      const int base = cloc[t2] * QS + t * BK + kq * 8;
      f16x8 b;
#pragma unroll
      for (int half = 0; half < 2; ++half) {
        const int4 q4 = *reinterpret_cast<const int4*>(&lqs[base + 4 * half]);
        const unsigned v0 = __builtin_amdgcn_ubfe((unsigned)q4.x, sh, 4);
        const unsigned v1 = __builtin_amdgcn_ubfe((unsigned)q4.y, sh, 4);
        const unsigned v2 = __builtin_amdgcn_ubfe((unsigned)q4.z, sh, 4);
        const unsigned v3 = __builtin_amdgcn_ubfe((unsigned)q4.w, sh, 4);
        const f16x2 h01 = __builtin_bit_cast(f16x2, (v0 | (v1 << 16)) | 0x64006400u);
        const f16x2 h23 = __builtin_bit_cast(f16x2, (v2 | (v3 << 16)) | 0x64006400u);
        const f16x2 w01 = (h01 + mz2[g][t2]) * s2[g][t2];   // exact (v-z), 1 rnd
        const f16x2 w23 = (h23 + mz2[g][t2]) * s2[g][t2];
        b[4 * half]     = w01[0];
        b[4 * half + 1] = w01[1];
        b[4 * half + 2] = w23[0];
        b[4 * half + 3] = w23[1];
      }
      acc[0][t2] = __builtin_amdgcn_mfma_f32_16x16x32_f16(a0, b, acc[0][t2], 0, 0, 0);
      acc[1][t2] = __builtin_amdgcn_mfma_f32_16x16x32_f16(a1, b, acc[1][t2], 0, 0, 0);
    }
  }

  _Float16* pp = partial + (long)by * OUT_ELEMS;
#pragma unroll
  for (int mt = 0; mt < 2; ++mt)
#pragma unroll
    for (int t2 = 0; t2 < 2; ++t2)
#pragma unroll
      for (int i = 0; i < 4; ++i) {
        const int row = mt * 16 + kq * 4 + i;
        pp[row * N + ncol[t2]] = (_Float16)acc[mt][t2][i];
      }
}

extern "C" void kernel_launch(void* const* d_in, const int* in_sizes, int n_in,
                              void* d_out, int out_size, void* d_ws, size_t ws_size,
                              hipStream_t stream) {
  const float* x    = (const float*)d_in[0];
  const int* qw     = (const int*)d_in[1];
  const int* qz     = (const int*)d_in[2];
  const float* sc   = (const float*)d_in[3];   // fp16 values delivered as f32
  const float* bias = (const float*)d_in[4];   // fp16 values delivered as f32
  float* out        = (float*)d_out;

  _Float16* partial = (_Float16*)d_ws;                       // 11.3 MB
  int* tiled        = (int*)((char*)d_ws + ((size_t)16 << 20));  // 22.5 MB tiled q

  transform_kernel<<<dim3(256), 512, 0, stream>>>(qw, tiled);
  awq_gemm_kernel<<<dim3(NWG), 512, 0, stream>>>(tiled, qz, sc, x, partial);
  reduce_kernel<<<dim3(OUT_ELEMS / (256 * 8)), 256, 0, stream>>>(partial, bias, out);
}